// Round 8
// baseline (626.793 us; speedup 1.0000x reference)
//
#include <hip/hip_runtime.h>

// SelfAttentionWithLeads v11: fused smax+pexp+gemm (v10 design) with
// compile-risk fix: the g-loop (trip count 8, ~112 MFMA body) is forced
// NOT to unroll (#pragma unroll 1). v10's fully-unrolled ~900-MFMA body at
// ~215 live VGPRs under a 256 cap is the suspected compile-stage container
// killer (2 rounds x 2 attempts failed with no compile diagnostic; all
// runtime accesses audit in-bounds and all barriers are uniform).
//   - P (67MB) never materialized: E tiles computed in-LDS per k-group.
//   - Sampled row max computed PER BLOCK from tile kt=nt (max cancels in
//     softmax normalization; per-block consistency suffices) -> no menc,
//     no smax kernel, no atomics. Numerics validated in v8/v9 (absmax
//     0.046875 bit-identical).
//   - lsum computed in-block (deterministic, replaces atomicAdd).
//   - h_t consumed via direct global 16B/lane loads at 2KB row stride (the
//     4 quads fully consume each 64B sector -> no over-fetch).
// Pipeline: wt -> proj -> fused   (3 dispatches).
// B=32, H=12, W=256, C=256, SPLIT=3 -> hs=4, N=1024, d_qk=96, d_v=768.
//
// d_ws layout (bytes):
//   Wt   @ 0         : [320][256] bf16  (Wf|Wg|Wh transposed)     163,840
//   f_fl @ 163840    : [32][1024][96] bf16                      6,291,456
//   g_fl @ 6455296   : [32][1024][96] bf16                      6,291,456
//   h_t  @ 12746752  : [32][768][1024] bf16 (pre-transposed)   50,331,648

typedef __bf16 bf16x8 __attribute__((ext_vector_type(8)));
typedef float f32x4 __attribute__((ext_vector_type(4)));

#define MFMA16 __builtin_amdgcn_mfma_f32_16x16x32_bf16

__device__ __forceinline__ short f2bf(float f) {
    unsigned u = __builtin_bit_cast(unsigned, f);
    u += 0x7fffu + ((u >> 16) & 1u);   // round-to-nearest-even
    return (short)(u >> 16);
}
__device__ __forceinline__ unsigned pack2bf(float a, float b) {
    return ((unsigned)(unsigned short)f2bf(a)) |
           (((unsigned)(unsigned short)f2bf(b)) << 16);
}

// ---------------------------------------------------------------- weights ---
__global__ __launch_bounds__(256) void wt_kernel(const float* __restrict__ Wf,
                                                 const float* __restrict__ Wg,
                                                 const float* __restrict__ Wh,
                                                 short* __restrict__ Wt) {
    int t = blockIdx.x * 256 + threadIdx.x;
    int j = t >> 8, k = t & 255;
    float v;
    if (j < 32)      v = Wf[k * 32 + j];
    else if (j < 64) v = Wg[k * 32 + (j - 32)];
    else             v = Wh[k * 256 + (j - 64)];
    Wt[j * 256 + k] = f2bf(v);
}

// ------------------------------------------------------------- projections --
// v9 structure (coalesced stores via LDS staging) unchanged.
__global__ __launch_bounds__(256) void proj_kernel(const float* __restrict__ x,
                                                   const short* __restrict__ Wt,
                                                   short* __restrict__ f_fl,
                                                   short* __restrict__ g_fl,
                                                   short* __restrict__ h_t) {
    const int tid = threadIdx.x;
    const int P0  = blockIdx.x * 64;
    const int b   = P0 / 3072;
    const int rem = P0 % 3072;
    const int hh  = rem >> 8;
    const int wbase = rem & 255;
    const int lead = hh >> 2, hsi = hh & 3;
    const int nbase = hsi * 256 + wbase;

    __shared__ __align__(16) short smem[18432];
    __shared__ __align__(16) short sf[64 * 40];
    __shared__ __align__(16) short sg[64 * 40];
    short* xs = smem;                       // [64][264]

    const float4* xv = (const float4*)(x + (size_t)P0 * 256);
    #pragma unroll
    for (int i = 0; i < 16; ++i) {
        int idx = i * 256 + tid;
        float4 v = xv[idx];
        int pix = idx >> 6;
        int col = (idx & 63) * 4;
        *(short4*)&xs[pix * 264 + col] =
            make_short4(f2bf(v.x), f2bf(v.y), f2bf(v.z), f2bf(v.w));
    }
    __syncthreads();

    const int lane = tid & 63, wv = tid >> 6;
    const int quad = lane >> 4, l15 = lane & 15;

    // ---- phase 1: f,g (rows = channels j) -> LDS sf/sg ----
    {
        const int jrow = wv * 16 + l15;
        f32x4 acc[4] = {};
        #pragma unroll
        for (int ki = 0; ki < 8; ++ki) {
            bf16x8 a = *(const bf16x8*)&Wt[jrow * 256 + ki * 32 + quad * 8];
            #pragma unroll
            for (int pt = 0; pt < 4; ++pt) {
                bf16x8 bb = *(const bf16x8*)&xs[(pt * 16 + l15) * 264 + ki * 32 + quad * 8];
                acc[pt] = MFMA16(a, bb, acc[pt], 0, 0, 0);
            }
        }
        short* sdst = (wv < 2) ? sf : sg;
        const int jloc = (wv & 1) * 16 + quad * 4;
        #pragma unroll
        for (int pt = 0; pt < 4; ++pt)
            *(short4*)&sdst[(pt * 16 + l15) * 40 + jloc] =
                make_short4(f2bf(acc[pt][0]), f2bf(acc[pt][1]),
                            f2bf(acc[pt][2]), f2bf(acc[pt][3]));
    }

    // ---- phase 2: h (rows = pixels, cols = out-channel cc) ----
    f32x4 acc2[4][4] = {};
    #pragma unroll
    for (int ki = 0; ki < 8; ++ki) {
        bf16x8 a[4], bb[4];
        #pragma unroll
        for (int pt = 0; pt < 4; ++pt)
            a[pt] = *(const bf16x8*)&xs[(pt * 16 + l15) * 264 + ki * 32 + quad * 8];
        #pragma unroll
        for (int ct = 0; ct < 4; ++ct)
            bb[ct] = *(const bf16x8*)&Wt[(64 + wv * 64 + ct * 16 + l15) * 256 + ki * 32 + quad * 8];
        #pragma unroll
        for (int pt = 0; pt < 4; ++pt)
            #pragma unroll
            for (int ct = 0; ct < 4; ++ct)
                acc2[pt][ct] = MFMA16(a[pt], bb[ct], acc2[pt][ct], 0, 0, 0);
    }
    __syncthreads();   // all xs reads done; all sf/sg writes visible

    // ---- acc2 -> sh (overlay on dead xs) ----
    short* sh = smem;                       // [256][72]
    #pragma unroll
    for (int pt = 0; pt < 4; ++pt)
        #pragma unroll
        for (int ct = 0; ct < 4; ++ct) {
            int cc = wv * 64 + ct * 16 + l15;
            *(short4*)&sh[cc * 72 + pt * 16 + quad * 4] =
                make_short4(f2bf(acc2[pt][ct][0]), f2bf(acc2[pt][ct][1]),
                            f2bf(acc2[pt][ct][2]), f2bf(acc2[pt][ct][3]));
        }

    // ---- coalesced f/g stores: 64 rows x 64B contiguous ----
    {
        int r = tid >> 2, c = (tid & 3) * 8;
        size_t gbase = ((size_t)b * 1024 + nbase + r) * 96 + lead * 32 + c;
        *(int4*)&f_fl[gbase] = *(const int4*)&sf[r * 40 + c];
        *(int4*)&g_fl[gbase] = *(const int4*)&sg[r * 40 + c];
    }
    __syncthreads();   // sh fully written

    // ---- coalesced h stores: 256 rows x 128B contiguous, 8 passes ----
    #pragma unroll
    for (int p = 0; p < 8; ++p) {
        int row = p * 32 + (tid >> 3);
        int c   = (tid & 7) * 8;
        *(int4*)&h_t[((size_t)b * 768 + lead * 256 + row) * 1024 + nbase + c] =
            *(const int4*)&sh[row * 72 + c];
    }
}

// ------------------------------------------------- fused S + softmax + PV ---
// Per block (mt = vc-slice of 128, nt = q-tile of 128, b):
//   g-frags resident in regs; phase0 computes sampled row max from tile kt=nt;
//   loop g=0..7 (NOT unrolled): S-tile (48 MFMA/wave) -> exp -> sP[128][136]
//   -> barrier -> PV (64 MFMA/wave, h_t direct-global A-frags) -> barrier.
//   lsum accumulated in regs, merged via LDS at the end.
__global__ __launch_bounds__(256, 2) void fused_kernel(const short* __restrict__ f_fl,
                                                       const short* __restrict__ g_fl,
                                                       const short* __restrict__ h_t,
                                                       const float* __restrict__ x,
                                                       const float* __restrict__ gammap,
                                                       float* __restrict__ out) {
    // 1536 blocks = 8 XCDs * (4 batches * 6 mt * 8 nt); nt innermost so
    // consecutive blocks on an XCD share the same 256KB h_t slice (L2-hot).
    const int wgid = blockIdx.x;
    const int xcd  = wgid & 7;
    const int slot = wgid >> 3;            // 0..191
    const int b    = xcd * 4 + (slot / 48);
    const int t    = slot % 48;
    const int mt   = t >> 3;               // 0..5  vc-slice
    const int nt   = t & 7;                // 0..7  q-tile

    const int tid = threadIdx.x, lane = tid & 63, wv = tid >> 6;
    const int quad = lane >> 4, l15 = lane & 15;
    const int wm = (wv & 1) * 64, wn = (wv >> 1) * 64;
    const int half = wv & 1;

    __shared__ __align__(16) short sP[128 * 136];   // E tile; rows 272B
    __shared__ float sM[2][128];
    __shared__ float sL[2][128];

    const short* gB    = g_fl + ((size_t)b * 1024 + nt * 128 + wn) * 96;
    const short* fBase = f_fl + ((size_t)b * 1024 + wm) * 96;
    const short* hB    = h_t  + ((size_t)b * 768 + mt * 128) * 1024;

    // g-frags: resident for the whole kernel (48 VGPR)
    bf16x8 bfr[4][3];
    #pragma unroll
    for (int j = 0; j < 4; ++j)
        #pragma unroll
        for (int ki = 0; ki < 3; ++ki)
            bfr[j][ki] = *(const bf16x8*)&gB[(j * 16 + l15) * 96 + ki * 32 + quad * 8];

    // ---- phase 0: sampled row max from tile kt = nt (cancels in softmax;
    //      per-block consistency is sufficient) ----
    {
        const short* fB = fBase + (size_t)(nt * 128) * 96;
        f32x4 acc[4][4] = {};
        #pragma unroll
        for (int i = 0; i < 4; ++i) {
            bf16x8 a[3];
            #pragma unroll
            for (int ki = 0; ki < 3; ++ki)
                a[ki] = *(const bf16x8*)&fB[(i * 16 + l15) * 96 + ki * 32 + quad * 8];
            #pragma unroll
            for (int j = 0; j < 4; ++j)
                #pragma unroll
                for (int ki = 0; ki < 3; ++ki)
                    acc[i][j] = MFMA16(a[ki], bfr[j][ki], acc[i][j], 0, 0, 0);
        }
        #pragma unroll
        for (int j = 0; j < 4; ++j) {
            float v = acc[0][j][0];
            #pragma unroll
            for (int i = 0; i < 4; ++i)
                #pragma unroll
                for (int r = 0; r < 4; ++r) v = fmaxf(v, acc[i][j][r]);
            v = fmaxf(v, __shfl_xor(v, 16));
            v = fmaxf(v, __shfl_xor(v, 32));
            if (quad == 0) sM[half][wn + j * 16 + l15] = v;
        }
    }
    __syncthreads();

    float mj[4], rsum[4];
    #pragma unroll
    for (int j = 0; j < 4; ++j) {
        int r = wn + j * 16 + l15;
        mj[j] = fmaxf(sM[0][r], sM[1][r]);
        rsum[j] = 0.f;
    }

    f32x4 accp[4][4] = {};   // PV accumulators (k-order == old gemm kt 0..31)

    #pragma unroll 1          // keep ONE ~112-MFMA body; full unroll (~900
    for (int g = 0; g < 8; ++g) {   // MFMA straight-line) is the suspected
                                    // compile-stage container killer
        // ---- S-tile quadrant ----
        const short* fB = fBase + (size_t)(g * 128) * 96;
        f32x4 acc[4][4] = {};
        #pragma unroll
        for (int i = 0; i < 4; ++i) {
            bf16x8 a[3];
            #pragma unroll
            for (int ki = 0; ki < 3; ++ki)
                a[ki] = *(const bf16x8*)&fB[(i * 16 + l15) * 96 + ki * 32 + quad * 8];
            #pragma unroll
            for (int j = 0; j < 4; ++j)
                #pragma unroll
                for (int ki = 0; ki < 3; ++ki)
                    acc[i][j] = MFMA16(a[ki], bfr[j][ki], acc[i][j], 0, 0, 0);
        }
        // ---- exp(s - m^), row-sum partials, E -> sP ----
        #pragma unroll 1
        for (int j = 0; j < 4; ++j) {
            const int qloc = wn + j * 16 + l15;
            float rs = 0.f;
            #pragma unroll
            for (int i = 0; i < 4; ++i) {
                float e0 = __expf(acc[i][j][0] - mj[j]);
                float e1 = __expf(acc[i][j][1] - mj[j]);
                float e2 = __expf(acc[i][j][2] - mj[j]);
                float e3 = __expf(acc[i][j][3] - mj[j]);
                rs += (e0 + e1) + (e2 + e3);
                uint2 w;
                w.x = pack2bf(e0, e1);
                w.y = pack2bf(e2, e3);
                *(uint2*)&sP[qloc * 136 + wm + i * 16 + quad * 4] = w;
            }
            rs += __shfl_xor(rs, 16);
            rs += __shfl_xor(rs, 32);
            rsum[j] += rs;
        }
        __syncthreads();   // sP tile complete (both wm halves)

        // ---- PV over this k-group: A = h_t direct-global, B = sP ----
        #pragma unroll
        for (int kk = 0; kk < 4; ++kk) {
            const int k0 = g * 128 + kk * 32;
            bf16x8 ah[4], bb[4];
            #pragma unroll
            for (int i = 0; i < 4; ++i)
                ah[i] = *(const bf16x8*)&hB[(size_t)(wm + i * 16 + l15) * 1024 + k0 + quad * 8];
            #pragma unroll
            for (int j = 0; j < 4; ++j)
                bb[j] = *(const bf16x8*)&sP[(wn + j * 16 + l15) * 136 + kk * 32 + quad * 8];
            #pragma unroll
            for (int i = 0; i < 4; ++i)
                #pragma unroll
                for (int j = 0; j < 4; ++j)
                    accp[i][j] = MFMA16(ah[i], bb[j], accp[i][j], 0, 0, 0);
        }
        __syncthreads();   // sP consumed; next g may overwrite
    }

    // ---- lsum merge (deterministic; replaces atomicAdd) ----
    #pragma unroll
    for (int j = 0; j < 4; ++j)
        if (quad == 0) sL[half][wn + j * 16 + l15] = rsum[j];
    __syncthreads();

    const float gamma = gammap[0];
    float gl[4];
    #pragma unroll
    for (int j = 0; j < 4; ++j) {
        int r = wn + j * 16 + l15;
        gl[j] = gamma / (sL[0][r] + sL[1][r]);
    }

    #pragma unroll
    for (int i = 0; i < 4; ++i)
        #pragma unroll
        for (int j = 0; j < 4; ++j) {
            int vc = mt * 128 + wm + i * 16 + quad * 4;   // 4 consecutive channels
            int qrow = nt * 128 + wn + j * 16 + l15;
            int lead = vc >> 8, c = vc & 255;
            int hsi = qrow >> 8, w_ = qrow & 255;
            size_t idx = (((size_t)b * 12 + lead * 4 + hsi) * 256 + w_) * 256 + c;
            float4 xv = *(const float4*)&x[idx];
            float4 ov;
            ov.x = gl[j] * accp[i][j][0] + xv.x;
            ov.y = gl[j] * accp[i][j][1] + xv.y;
            ov.z = gl[j] * accp[i][j][2] + xv.z;
            ov.w = gl[j] * accp[i][j][3] + xv.w;
            *(float4*)&out[idx] = ov;
        }
}

// ------------------------------------------------------------------ launch --
extern "C" void kernel_launch(void* const* d_in, const int* in_sizes, int n_in,
                              void* d_out, int out_size, void* d_ws, size_t ws_size,
                              hipStream_t stream) {
    const float* x     = (const float*)d_in[0];
    const float* Wf    = (const float*)d_in[1];
    const float* Wg    = (const float*)d_in[2];
    const float* Wh    = (const float*)d_in[3];
    const float* gamma = (const float*)d_in[4];
    float* out = (float*)d_out;

    char* ws = (char*)d_ws;
    short* Wt   = (short*)(ws + 0);
    short* f_fl = (short*)(ws + 163840);
    short* g_fl = (short*)(ws + 6455296);
    short* h_t  = (short*)(ws + 12746752);

    wt_kernel<<<dim3(320), dim3(256), 0, stream>>>(Wf, Wg, Wh, Wt);
    proj_kernel<<<dim3(1536), dim3(256), 0, stream>>>(x, Wt, f_fl, g_fl, h_t);
    fused_kernel<<<dim3(1536), dim3(256), 0, stream>>>(f_fl, g_fl, h_t, x, gamma, out);
}